// Round 4
// baseline (2727.168 us; speedup 1.0000x reference)
//
#include <hip/hip_runtime.h>
#include <math.h>

constexpr int Bc = 4, Nc = 32768, Cc = 256, Hc = 8, CHc = 64, Mc = 64, INNERc = 512;

typedef _Float16 h8 __attribute__((ext_vector_type(8)));
typedef _Float16 h4 __attribute__((ext_vector_type(4)));
typedef float f32x4 __attribute__((ext_vector_type(4)));

__device__ __forceinline__ void fma4x4(float acc[4][4], const float4 a, const float4 b) {
  acc[0][0] += a.x*b.x; acc[0][1] += a.x*b.y; acc[0][2] += a.x*b.z; acc[0][3] += a.x*b.w;
  acc[1][0] += a.y*b.x; acc[1][1] += a.y*b.y; acc[1][2] += a.y*b.z; acc[1][3] += a.y*b.w;
  acc[2][0] += a.z*b.x; acc[2][1] += a.z*b.y; acc[2][2] += a.z*b.z; acc[2][3] += a.z*b.w;
  acc[3][0] += a.w*b.x; acc[3][1] += a.w*b.y; acc[3][2] += a.w*b.z; acc[3][3] += a.w*b.w;
}

// ============================================================================
// xplanes: f32 [rows][256] -> interleaved f16 hi/lo planes [rows][512]:
//   octet g (k=8g..8g+7): hi h8 at f16-offset 16g, lo h8 at 16g+8.
//   This is EXACTLY the MFMA A-frag layout: lane loads 32B at (row, 16g).
// ============================================================================
__global__ __launch_bounds__(256)
void xplanes_kernel(const float* __restrict__ src, _Float16* __restrict__ dst)
{
  const long idx = (long)blockIdx.x * 256 + threadIdx.x;   // octet id
  const long row = idx >> 5, oc = idx & 31;
  const float4 a = *(const float4*)&src[(row << 8) + (oc << 3)];
  const float4 b = *(const float4*)&src[(row << 8) + (oc << 3) + 4];
  const float va[8] = {a.x, a.y, a.z, a.w, b.x, b.y, b.z, b.w};
  h8 hv, lv;
#pragma unroll
  for (int j = 0; j < 8; ++j) {
    const _Float16 hi = (_Float16)va[j];
    hv[j] = hi; lv[j] = (_Float16)(va[j] - (float)hi);
  }
  *(h8*)&dst[(row << 9) + (oc << 4)]     = hv;
  *(h8*)&dst[(row << 9) + (oc << 4) + 8] = lv;
}

// ============================================================================
// project_token: merged x/xc via blockIdx.z. Stage-1 A-frags come DIRECTLY
// from the f16 hi/lo planes (no LDS staging, no per-tile convert, no staging
// barriers -> 4 barriers/tile). If xc-planes don't fit in ws (Xic==nullptr),
// those blocks use the verbatim round-3 staged path.
// LDS: Xst (fallback only) 20.5K + FXT 18.4K + XMT 18.4K = 57,344 B
//      (Sred overlays Xst).
// ============================================================================
__global__ __launch_bounds__(256, 2)
void project_token_kernel(const float* __restrict__ Xx, const float* __restrict__ Xc,
                          const _Float16* __restrict__ Xix, const _Float16* __restrict__ Xic,
                          const float* __restrict__ Wfx, const float* __restrict__ bfx,
                          const float* __restrict__ Wx, const float* __restrict__ bx,
                          const float* __restrict__ Wsl, const float* __restrict__ bsl,
                          const float* __restrict__ temp,
                          float* __restrict__ TUx, float* __restrict__ TUc,
                          float* __restrict__ Ssx, float* __restrict__ Ssc)
{
  __shared__ __align__(16) _Float16 Xst[2][2][64][40];  // fallback staging only
  __shared__ __align__(16) _Float16 FXT[2][64][72];     // [hi/lo][c][tok]
  __shared__ __align__(16) _Float16 XMT[2][64][72];     // [hi/lo][tok][c] -> swT[hi/lo][g][tok]
  float (*Sred)[64] = (float(*)[64])&Xst[0][0][0][0];   // overlay (tail use only)

  const int t = threadIdx.x;
  const int chunk = blockIdx.x, h = blockIdx.y, bz = blockIdx.z;
  const int b = bz & 3;
  const float* X = (bz < 4) ? Xx : Xc;
  const _Float16* Xi = (bz < 4) ? Xix : Xic;
  float* TU   = (bz < 4) ? TUx : TUc;
  float* Ssum = (bz < 4) ? Ssx : Ssc;
  const int bh = b * Hc + h, colBase = h * 64;
  const int w = t >> 6, l = t & 63, lg = l >> 4, lr = l & 15;
  const int stok = t >> 2, sc8 = (t & 3) << 3;

  const float invt = 1.0f / fminf(fmaxf(temp[h], 0.1f), 5.0f);

  // ---- stage-1 W frags: waves 0,1 -> Wfx cols, waves 2,3 -> Wx cols ----
  const float* Wsrc = (w < 2) ? Wfx : Wx;
  const float* bsrc = (w < 2) ? bfx : bx;
  const int wcb = colBase + ((w & 1) << 5);
  h8 wfh[8][2], wfl[8][2];
  float biasv[2];
#pragma unroll
  for (int n = 0; n < 2; ++n) {
    const int col = wcb + (n << 4) + lr;
    biasv[n] = bsrc[col];
#pragma unroll
    for (int ks = 0; ks < 8; ++ks)
#pragma unroll
      for (int j = 0; j < 8; ++j) {
        const float v = Wsrc[(long)((ks << 5) + (lg << 3) + j) * INNERc + col];
        const _Float16 hi = (_Float16)v;
        wfh[ks][n][j] = hi;
        wfl[ks][n][j] = (_Float16)(v - (float)hi);
      }
  }
  // ---- Wsl frags (all 64 g per wave) ----
  h8 wslh[2][4], wsll[2][4];
#pragma unroll
  for (int ks = 0; ks < 2; ++ks)
#pragma unroll
    for (int n = 0; n < 4; ++n)
#pragma unroll
      for (int j = 0; j < 8; ++j) {
        const float v = Wsl[((ks << 5) + (lg << 3) + j) * 64 + (n << 4) + lr];
        const _Float16 hi = (_Float16)v;
        wslh[ks][n][j] = hi;
        wsll[ks][n][j] = (_Float16)(v - (float)hi);
      }
  float bs_n[4];
#pragma unroll
  for (int n = 0; n < 4; ++n) bs_n[n] = bsl[(n << 4) + lr];

  f32x4 tuacc[4] = {};
  float sregn[4] = {};

  for (int tile = 0; tile < 32; ++tile) {
    const int n0 = chunk * 2048 + tile * 64;
    f32x4 acc[4][2] = {};

    if (Xi) {
      // ---- stage 1 (planes): barrier-free, direct global A-frags ----
      __syncthreads();   // prev tile stage-4 FXT/swT reads done before epilogue writes
      const long rbase = ((long)(b * Nc + n0)) * 512;
#pragma unroll
      for (int ks = 0; ks < 8; ++ks) {
#pragma unroll
        for (int m = 0; m < 4; ++m) {
          const h8* p = (const h8*)&Xi[rbase + (long)((m << 4) + lr) * 512 + (((ks << 2) + lg) << 4)];
          const h8 ah = p[0], al = p[1];
#pragma unroll
          for (int n = 0; n < 2; ++n) {
            acc[m][n] = __builtin_amdgcn_mfma_f32_16x16x32_f16(ah, wfh[ks][n], acc[m][n], 0, 0, 0);
            acc[m][n] = __builtin_amdgcn_mfma_f32_16x16x32_f16(al, wfh[ks][n], acc[m][n], 0, 0, 0);
            acc[m][n] = __builtin_amdgcn_mfma_f32_16x16x32_f16(ah, wfl[ks][n], acc[m][n], 0, 0, 0);
          }
        }
      }
    } else {
      // ---- stage 1 (fallback, verbatim staged path) ----
      const long xRow = ((long)(b * Nc + n0 + stok)) * Cc + sc8;
      {
        const float4 xa = *(const float4*)&X[xRow];
        const float4 xb = *(const float4*)&X[xRow + 4];
        const float va[8] = {xa.x, xa.y, xa.z, xa.w, xb.x, xb.y, xb.z, xb.w};
        h8 hv, lv;
#pragma unroll
        for (int j = 0; j < 8; ++j) {
          const _Float16 hi = (_Float16)va[j];
          hv[j] = hi; lv[j] = (_Float16)(va[j] - (float)hi);
        }
        *(h8*)&Xst[0][0][stok][sc8] = hv;
        *(h8*)&Xst[0][1][stok][sc8] = lv;
      }
#pragma unroll
      for (int ks = 0; ks < 8; ++ks) {
        const int cb = ks & 1;
        __syncthreads();
        float4 xa, xb;
        if (ks < 7) {
          xa = *(const float4*)&X[xRow + ((ks + 1) << 5)];
          xb = *(const float4*)&X[xRow + ((ks + 1) << 5) + 4];
        }
#pragma unroll
        for (int m = 0; m < 4; ++m) {
          const h8 ah = *(const h8*)&Xst[cb][0][(m << 4) + lr][lg << 3];
          const h8 al = *(const h8*)&Xst[cb][1][(m << 4) + lr][lg << 3];
#pragma unroll
          for (int n = 0; n < 2; ++n) {
            acc[m][n] = __builtin_amdgcn_mfma_f32_16x16x32_f16(ah, wfh[ks][n], acc[m][n], 0, 0, 0);
            acc[m][n] = __builtin_amdgcn_mfma_f32_16x16x32_f16(al, wfh[ks][n], acc[m][n], 0, 0, 0);
            acc[m][n] = __builtin_amdgcn_mfma_f32_16x16x32_f16(ah, wfl[ks][n], acc[m][n], 0, 0, 0);
          }
        }
        if (ks < 7) {
          const float va[8] = {xa.x, xa.y, xa.z, xa.w, xb.x, xb.y, xb.z, xb.w};
          h8 hv, lv;
#pragma unroll
          for (int j = 0; j < 8; ++j) {
            const _Float16 hi = (_Float16)va[j];
            hv[j] = hi; lv[j] = (_Float16)(va[j] - (float)hi);
          }
          *(h8*)&Xst[cb ^ 1][0][stok][sc8] = hv;
          *(h8*)&Xst[cb ^ 1][1][stok][sc8] = lv;
        }
      }
    }

    // ---- epilogue: FX (waves 0,1) / XM (waves 2,3) as f16 hi/lo ----
    // C layout: col = lane&15, row = 4*(lane>>4)+reg  [HW-verified]
    if (w < 2) {
#pragma unroll
      for (int m = 0; m < 4; ++m)
#pragma unroll
        for (int n = 0; n < 2; ++n) {
          const int c = ((w & 1) << 5) + (n << 4) + lr;
          const int tokb = (m << 4) + (lg << 2);
          h4 hv, lv;
#pragma unroll
          for (int i = 0; i < 4; ++i) {
            const float v = acc[m][n][i] + biasv[n];
            const _Float16 hi = (_Float16)v;
            hv[i] = hi; lv[i] = (_Float16)(v - (float)hi);
          }
          *(h4*)&FXT[0][c][tokb] = hv;
          *(h4*)&FXT[1][c][tokb] = lv;
        }
    } else {
#pragma unroll
      for (int m = 0; m < 4; ++m)
#pragma unroll
        for (int n = 0; n < 2; ++n) {
          const int c = ((w & 1) << 5) + (n << 4) + lr;
#pragma unroll
          for (int i = 0; i < 4; ++i) {
            const float v = acc[m][n][i] + biasv[n];
            const _Float16 hi = (_Float16)v;
            XMT[0][(m << 4) + (lg << 2) + i][c] = hi;
            XMT[1][(m << 4) + (lg << 2) + i][c] = (_Float16)(v - (float)hi);
          }
        }
    }
    __syncthreads();

    // ---- stage 2: logits = XM @ Wsl (wave w: tokens 16w..16w+15) ----
    f32x4 lga[4] = {};
#pragma unroll
    for (int ks = 0; ks < 2; ++ks) {
      const h8 ah = *(const h8*)&XMT[0][(w << 4) + lr][(ks << 5) + (lg << 3)];
      const h8 al = *(const h8*)&XMT[1][(w << 4) + lr][(ks << 5) + (lg << 3)];
#pragma unroll
      for (int n = 0; n < 4; ++n) {
        lga[n] = __builtin_amdgcn_mfma_f32_16x16x32_f16(ah, wslh[ks][n], lga[n], 0, 0, 0);
        lga[n] = __builtin_amdgcn_mfma_f32_16x16x32_f16(al, wslh[ks][n], lga[n], 0, 0, 0);
        lga[n] = __builtin_amdgcn_mfma_f32_16x16x32_f16(ah, wsll[ks][n], lga[n], 0, 0, 0);
      }
    }
    __syncthreads();   // XMT reads done before swT overlay writes

    // ---- stage 3: softmax over g; token = 16w+4lg+i, g = 16n+lr ----
    float sw[4][4];    // [n][i]
#pragma unroll
    for (int i = 0; i < 4; ++i) {
      float mx = -1e30f;
#pragma unroll
      for (int n = 0; n < 4; ++n) {
        const float lv = (lga[n][i] + bs_n[n]) * invt;
        sw[n][i] = lv; mx = fmaxf(mx, lv);
      }
      for (int d = 1; d < 16; d <<= 1) mx = fmaxf(mx, __shfl_xor(mx, d));
      float s = 0.f;
#pragma unroll
      for (int n = 0; n < 4; ++n) { sw[n][i] = __expf(sw[n][i] - mx); s += sw[n][i]; }
      for (int d = 1; d < 16; d <<= 1) s += __shfl_xor(s, d);
      const float inv = 1.0f / s;
#pragma unroll
      for (int n = 0; n < 4; ++n) { sw[n][i] *= inv; sregn[n] += sw[n][i]; }
    }
    // write swT[g][tok] hi/lo into dead XM buffers
#pragma unroll
    for (int n = 0; n < 4; ++n) {
      h4 hv, lv;
#pragma unroll
      for (int i = 0; i < 4; ++i) {
        const _Float16 hi = (_Float16)sw[n][i];
        hv[i] = hi; lv[i] = (_Float16)(sw[n][i] - (float)hi);
      }
      *(h4*)&XMT[0][(n << 4) + lr][(w << 4) + (lg << 2)] = hv;
      *(h4*)&XMT[1][(n << 4) + lr][(w << 4) + (lg << 2)] = lv;
    }
    __syncthreads();

    // ---- stage 4: TU[g][c] += sw^T @ FX (wave w: g rows 16w..16w+15) ----
#pragma unroll
    for (int ks = 0; ks < 2; ++ks) {
      const h8 ah = *(const h8*)&XMT[0][(w << 4) + lr][(ks << 5) + (lg << 3)];
      const h8 al = *(const h8*)&XMT[1][(w << 4) + lr][(ks << 5) + (lg << 3)];
#pragma unroll
      for (int n = 0; n < 4; ++n) {
        const h8 bhv = *(const h8*)&FXT[0][(n << 4) + lr][(ks << 5) + (lg << 3)];
        const h8 blv = *(const h8*)&FXT[1][(n << 4) + lr][(ks << 5) + (lg << 3)];
        tuacc[n] = __builtin_amdgcn_mfma_f32_16x16x32_f16(ah, bhv, tuacc[n], 0, 0, 0);
        tuacc[n] = __builtin_amdgcn_mfma_f32_16x16x32_f16(al, bhv, tuacc[n], 0, 0, 0);
        tuacc[n] = __builtin_amdgcn_mfma_f32_16x16x32_f16(ah, blv, tuacc[n], 0, 0, 0);
      }
    }
    // next tile's leading barrier covers the FXT/swT read-vs-write hazards
  }

  // ---- TU atomics: g = 16w+4lg+i, c = 16n+lr ----
#pragma unroll
  for (int n = 0; n < 4; ++n)
#pragma unroll
    for (int i = 0; i < 4; ++i)
      atomicAdd(&TU[((long)bh * 64 + (w << 4) + (lg << 2) + i) * 64 + (n << 4) + lr],
                tuacc[n][i]);

  // ---- Ssum reduce (Sred overlays Xst) ----
  __syncthreads();
#pragma unroll
  for (int n = 0; n < 4; ++n) Sred[(w << 2) + lg][(n << 4) + lr] = sregn[n];
  __syncthreads();
  if (t < 64) {
    float s = 0.f;
    for (int r = 0; r < 16; ++r) s += Sred[r][t];
    atomicAdd(&Ssum[bh * 64 + t], s);
  }
}

// ============================================================================
// att (unchanged)
// ============================================================================
__global__ __launch_bounds__(64)
void att_kernel(const float* __restrict__ TUx, const float* __restrict__ TUc,
                const float* __restrict__ Sx, const float* __restrict__ Sc,
                const float* __restrict__ Wq, const float* __restrict__ Wk,
                const float* __restrict__ Wv, float* __restrict__ OT)
{
  __shared__ __align__(16) float W[64][68];
  __shared__ __align__(16) float Km[64][68];
  __shared__ __align__(16) float Vm[64][68];
  const int bh = blockIdx.x;
  const int g  = threadIdx.x;
  const float invc = 1.0f / (Sc[bh * 64 + g] + 1e-5f);
  const float invx = 1.0f / (Sx[bh * 64 + g] + 1e-5f);

  for (int i = 0; i < 64; ++i) W[i][g] = Wk[i * 64 + g];
  __syncthreads();
  {
    float4 a[16]; for (int j = 0; j < 16; ++j) a[j] = make_float4(0,0,0,0);
    for (int c = 0; c < 64; ++c) {
      const float tc = TUc[((long)bh * 64 + g) * 64 + c] * invc;
#pragma unroll
      for (int j = 0; j < 16; ++j) {
        const float4 w4 = *(const float4*)&W[c][j << 2];
        a[j].x += tc*w4.x; a[j].y += tc*w4.y; a[j].z += tc*w4.z; a[j].w += tc*w4.w;
      }
    }
    for (int j = 0; j < 16; ++j) *(float4*)&Km[g][j << 2] = a[j];
  }
  __syncthreads();
  for (int i = 0; i < 64; ++i) W[i][g] = Wv[i * 64 + g];
  __syncthreads();
  {
    float4 a[16]; for (int j = 0; j < 16; ++j) a[j] = make_float4(0,0,0,0);
    for (int c = 0; c < 64; ++c) {
      const float tc = TUc[((long)bh * 64 + g) * 64 + c] * invc;
#pragma unroll
      for (int j = 0; j < 16; ++j) {
        const float4 w4 = *(const float4*)&W[c][j << 2];
        a[j].x += tc*w4.x; a[j].y += tc*w4.y; a[j].z += tc*w4.z; a[j].w += tc*w4.w;
      }
    }
    for (int j = 0; j < 16; ++j) *(float4*)&Vm[g][j << 2] = a[j];
  }
  __syncthreads();
  for (int i = 0; i < 64; ++i) W[i][g] = Wq[i * 64 + g];
  __syncthreads();
  float4 qa[16]; for (int j = 0; j < 16; ++j) qa[j] = make_float4(0,0,0,0);
  for (int c = 0; c < 64; ++c) {
    const float tq = TUx[((long)bh * 64 + g) * 64 + c] * invx;
#pragma unroll
    for (int j = 0; j < 16; ++j) {
      const float4 w4 = *(const float4*)&W[c][j << 2];
      qa[j].x += tq*w4.x; qa[j].y += tq*w4.y; qa[j].z += tq*w4.z; qa[j].w += tq*w4.w;
    }
  }
  __syncthreads();
  float (*Am)[68] = W;
  float mx = -1e30f;
  for (int m = 0; m < 64; ++m) {
    float s = 0.f;
#pragma unroll
    for (int j = 0; j < 16; ++j) {
      const float4 k4 = *(const float4*)&Km[m][j << 2];
      s += qa[j].x*k4.x + qa[j].y*k4.y + qa[j].z*k4.z + qa[j].w*k4.w;
    }
    s *= 0.125f;
    Am[m][g] = s;
    mx = fmaxf(mx, s);
  }
  float sum = 0.f;
  for (int m = 0; m < 64; ++m) { const float ev = __expf(Am[m][g] - mx); Am[m][g] = ev; sum += ev; }
  float4 oa[16]; for (int j = 0; j < 16; ++j) oa[j] = make_float4(0,0,0,0);
  for (int m = 0; m < 64; ++m) {
    const float am = Am[m][g];
#pragma unroll
    for (int j = 0; j < 16; ++j) {
      const float4 v4 = *(const float4*)&Vm[m][j << 2];
      oa[j].x += am*v4.x; oa[j].y += am*v4.y; oa[j].z += am*v4.z; oa[j].w += am*v4.w;
    }
  }
  const float so = invx / sum;
#pragma unroll
  for (int j = 0; j < 16; ++j) {
    OT[((long)bh * 64 + ((j<<2)+0)) * 64 + g] = oa[j].x * so;
    OT[((long)bh * 64 + ((j<<2)+1)) * 64 + g] = oa[j].y * so;
    OT[((long)bh * 64 + ((j<<2)+2)) * 64 + g] = oa[j].z * so;
    OT[((long)bh * 64 + ((j<<2)+3)) * 64 + g] = oa[j].w * so;
  }
}

// ============================================================================
// wofold (unchanged): emits WoT transposed f16 hi/lo [bh][co][g]
// ============================================================================
__global__ __launch_bounds__(256)
void wofold_kernel(const float* __restrict__ OT, const float* __restrict__ Wo,
                   _Float16* __restrict__ WoTth, _Float16* __restrict__ WoTtl)
{
  __shared__ __align__(16) float OTs[64][68];
  __shared__ __align__(16) float Wos[64][68];
  const int t = threadIdx.x, tx = t & 15, ty = t >> 4;
  const int cot = blockIdx.x * 64, bh = blockIdx.y, h = bh & 7;
#pragma unroll
  for (int rep = 0; rep < 4; ++rep) {
    const int v = t + rep * 256, r = v >> 4, q4 = (v & 15) << 2;
    *(float4*)&OTs[r][q4] = *(const float4*)&OT[((long)bh * 64 + r) * 64 + q4];
    *(float4*)&Wos[r][q4] = *(const float4*)&Wo[(long)(h * 64 + r) * 256 + cot + q4];
  }
  __syncthreads();
  float acc[4][4] = {};
#pragma unroll
  for (int k = 0; k < 64; ++k) {
    const float4 a = *(const float4*)&OTs[k][ty << 2];
    fma4x4(acc, a, *(const float4*)&Wos[k][tx << 2]);
  }
#pragma unroll
  for (int i = 0; i < 4; ++i)
#pragma unroll
    for (int j = 0; j < 4; ++j) {
      const float v = acc[i][j];
      const _Float16 hi = (_Float16)v;
      const long o = ((long)bh * 256 + cot + (tx<<2)+j) * 64 + (ty<<2)+i;
      WoTth[o] = hi;
      WoTtl[o] = (_Float16)(v - (float)hi);
    }
}

// ============================================================================
// wxprep (unchanged): Wx -> Wxth/Wxtl[col][k] f16 hi/lo
// ============================================================================
__global__ __launch_bounds__(256)
void wxprep_kernel(const float* __restrict__ Wx, _Float16* __restrict__ Wxth,
                   _Float16* __restrict__ Wxtl)
{
  __shared__ __align__(16) float Ls[64][68];
  const int t = threadIdx.x;
  const int k0 = blockIdx.x * 64, c0 = blockIdx.y * 64;
  const int r = t >> 4, c4 = (t & 15) << 2;
#pragma unroll
  for (int rr = 0; rr < 4; ++rr)
    *(float4*)&Ls[(rr<<4)+r][c4] = *(const float4*)&Wx[(long)(k0+(rr<<4)+r) * 512 + c0 + c4];
  __syncthreads();
  const int cl = t >> 2, kq = (t & 3) << 4;
  h8 hv0, hv1, lv0, lv1;
#pragma unroll
  for (int kk = 0; kk < 8; ++kk) {
    float v = Ls[kq+kk][cl];
    _Float16 hi = (_Float16)v;
    hv0[kk] = hi; lv0[kk] = (_Float16)(v - (float)hi);
    v = Ls[kq+8+kk][cl];
    hi = (_Float16)v;
    hv1[kk] = hi; lv1[kk] = (_Float16)(v - (float)hi);
  }
  const long o = (long)(c0 + cl) * 256 + k0 + kq;
  *(h8*)&Wxth[o]     = hv0; *(h8*)&Wxth[o + 8] = hv1;
  *(h8*)&Wxtl[o]     = lv0; *(h8*)&Wxtl[o + 8] = lv1;
}

// ============================================================================
// outx (REWRITTEN): A-frags direct from x planes (which live in d_out — every
// block only reads its own 64 rows and overwrites them in the epilogue, after
// all reads, with a true data dependency through oacc).
// Per head: XM (global A-frags, barrier-free) -> logits+softmax in-reg
// (PT partition: wave owns 16 tokens, all 64 g) -> sw overlay -> out += sw@WoT.
// LDS: XMT 36,864 B only -> 2 blocks/CU (VGPR-bound).
// ============================================================================
__global__ __launch_bounds__(256, 2)
void outx_kernel(const _Float16* Xi, const _Float16* __restrict__ Wxth,
                 const _Float16* __restrict__ Wxtl, const float* __restrict__ bx,
                 const float* __restrict__ Wsl, const float* __restrict__ bsl,
                 const float* __restrict__ temp,
                 const _Float16* __restrict__ WoTth, const _Float16* __restrict__ WoTtl,
                 const float* __restrict__ bo, float* out)
{
  __shared__ __align__(16) _Float16 XMT[2][64][72];  // [hi/lo][tok][c] -> sw[tok][g]

  const int t = threadIdx.x;
  const int w = t >> 6, l = t & 63, lg = l >> 4, lr = l & 15;
  const int n0 = blockIdx.x * 64, b = blockIdx.y;
  const long rbase = ((long)b * Nc + n0) * 512;

  // ---- Wsl frags: all 64 g (hi/lo) ----
  h8 wslh[2][4], wsll[2][4];
#pragma unroll
  for (int ks = 0; ks < 2; ++ks)
#pragma unroll
    for (int n = 0; n < 4; ++n)
#pragma unroll
      for (int j = 0; j < 8; ++j) {
        const float v = Wsl[((ks << 5) + (lg << 3) + j) * 64 + (n << 4) + lr];
        const _Float16 hi = (_Float16)v;
        wslh[ks][n][j] = hi; wsll[ks][n][j] = (_Float16)(v - (float)hi);
      }
  float bs_n[4];
#pragma unroll
  for (int n = 0; n < 4; ++n) bs_n[n] = bsl[(n << 4) + lr];

  f32x4 oacc[4][4] = {};

  for (int h = 0; h < Hc; ++h) {
    // ---- Wx frags for this head (wave col = 16w+lr) ----
    h8 wxh[8], wxl[8];
    const long wxoff = (long)((h << 6) + (w << 4) + lr) * 256 + (lg << 3);
#pragma unroll
    for (int ks = 0; ks < 8; ++ks) {
      wxh[ks] = *(const h8*)&Wxth[wxoff + (ks << 5)];
      wxl[ks] = *(const h8*)&Wxtl[wxoff + (ks << 5)];
    }
    const float bxv = bx[(h << 6) + (w << 4) + lr];
    const float invt = 1.0f / fminf(fmaxf(temp[h], 0.1f), 5.0f);

    // ---- stage 1: XM = X@Wx_h via direct global A-frags (barrier-free) ----
    f32x4 xma[4] = {};
#pragma unroll
    for (int ks = 0; ks < 8; ++ks) {
#pragma unroll
      for (int m = 0; m < 4; ++m) {
        const h8* p = (const h8*)&Xi[rbase + (long)((m << 4) + lr) * 512 + (((ks << 2) + lg) << 4)];
        const h8 ah = p[0], al = p[1];
        xma[m] = __builtin_amdgcn_mfma_f32_16x16x32_f16(ah, wxh[ks], xma[m], 0, 0, 0);
        xma[m] = __builtin_amdgcn_mfma_f32_16x16x32_f16(al, wxh[ks], xma[m], 0, 0, 0);
        xma[m] = __builtin_amdgcn_mfma_f32_16x16x32_f16(ah, wxl[ks], xma[m], 0, 0, 0);
      }
    }
    __syncthreads();   // prev head's stage-4 sw reads done before XM writes
#pragma unroll
    for (int m = 0; m < 4; ++m)
#pragma unroll
      for (int i = 0; i < 4; ++i) {
        const float v = xma[m][i] + bxv;
        const _Float16 hi = (_Float16)v;
        XMT[0][(m << 4) + (lg << 2) + i][(w << 4) + lr] = hi;
        XMT[1][(m << 4) + (lg << 2) + i][(w << 4) + lr] = (_Float16)(v - (float)hi);
      }
    __syncthreads();

    // ---- WoT frags for this head (issue early) ----
    const int bh = (b << 3) + h;
    h8 wth[4][2], wtl[4][2];
#pragma unroll
    for (int n = 0; n < 4; ++n)
#pragma unroll
      for (int ks = 0; ks < 2; ++ks) {
        const long o = ((long)(bh << 8) + (w << 6) + (n << 4) + lr) * 64 + (ks << 5) + (lg << 3);
        wth[n][ks] = *(const h8*)&WoTth[o];
        wtl[n][ks] = *(const h8*)&WoTtl[o];
      }

    // ---- stage 2: logits = XM @ Wsl (wave w: tokens 16w..16w+15, all g) ----
    f32x4 lga[4] = {};
#pragma unroll
    for (int ks = 0; ks < 2; ++ks) {
      const h8 ah = *(const h8*)&XMT[0][(w << 4) + lr][(ks << 5) + (lg << 3)];
      const h8 al = *(const h8*)&XMT[1][(w << 4) + lr][(ks << 5) + (lg << 3)];
#pragma unroll
      for (int n = 0; n < 4; ++n) {
        lga[n] = __builtin_amdgcn_mfma_f32_16x16x32_f16(ah, wslh[ks][n], lga[n], 0, 0, 0);
        lga[n] = __builtin_amdgcn_mfma_f32_16x16x32_f16(al, wslh[ks][n], lga[n], 0, 0, 0);
        lga[n] = __builtin_amdgcn_mfma_f32_16x16x32_f16(ah, wsll[ks][n], lga[n], 0, 0, 0);
      }
    }
    __syncthreads();   // XMT reads done before sw overlay

    // ---- stage 3: softmax over g; token = 16w+4lg+i, g = 16n+lr ----
    float sw[4][4];
#pragma unroll
    for (int i = 0; i < 4; ++i) {
      float mx = -1e30f;
#pragma unroll
      for (int n = 0; n < 4; ++n) {
        const float lv = (lga[n][i] + bs_n[n]) * invt;
        sw[n][i] = lv; mx = fmaxf(mx, lv);
      }
      for (int d = 1; d < 16; d <<= 1) mx = fmaxf(mx, __shfl_xor(mx, d));
      float s = 0.f;
#pragma unroll
      for (int n = 0; n < 4; ++n) { sw[n][i] = __expf(sw[n][i] - mx); s += sw[n][i]; }
      for (int d = 1; d < 16; d <<= 1) s += __shfl_xor(s, d);
      const float inv = 1.0f / s;
#pragma unroll
      for (int n = 0; n < 4; ++n) sw[n][i] *= inv;
    }
    // write sw [tok][g] hi/lo over dead XM
#pragma unroll
    for (int n = 0; n < 4; ++n)
#pragma unroll
      for (int i = 0; i < 4; ++i) {
        const _Float16 hi = (_Float16)sw[n][i];
        XMT[0][(w << 4) + (lg << 2) + i][(n << 4) + lr] = hi;
        XMT[1][(w << 4) + (lg << 2) + i][(n << 4) + lr] = (_Float16)(sw[n][i] - (float)hi);
      }
    __syncthreads();

    // ---- stage 4: out += sw @ WoT (A = sw[tok][g], wave owns 64 co) ----
#pragma unroll
    for (int ks = 0; ks < 2; ++ks)
#pragma unroll
      for (int m = 0; m < 4; ++m) {
        const h8 ah = *(const h8*)&XMT[0][(m << 4) + lr][(ks << 5) + (lg << 3)];
        const h8 al = *(const h8*)&XMT[1][(m << 4) + lr][(ks << 5) + (lg << 3)];
#pragma unroll
        for (int n = 0; n < 4; ++n) {
          oacc[m][n] = __builtin_amdgcn_mfma_f32_16x16x32_f16(ah, wth[n][ks], oacc[m][n], 0, 0, 0);
          oacc[m][n] = __builtin_amdgcn_mfma_f32_16x16x32_f16(al, wth[n][ks], oacc[m][n], 0, 0, 0);
          oacc[m][n] = __builtin_amdgcn_mfma_f32_16x16x32_f16(ah, wtl[n][ks], oacc[m][n], 0, 0, 0);
        }
      }
    // next head's pre-XM-write barrier covers the sw read hazard
  }

  // ---- epilogue: overwrite the plane rows with the final output ----
#pragma unroll
  for (int n = 0; n < 4; ++n) {
    const float bov = bo[(w << 6) + (n << 4) + lr];
#pragma unroll
    for (int m = 0; m < 4; ++m)
#pragma unroll
      for (int i = 0; i < 4; ++i)
        out[((long)b * Nc + n0 + (m << 4) + (lg << 2) + i) * 256 + (w << 6) + (n << 4) + lr]
            = oacc[m][n][i] + bov;
  }
}

extern "C" void kernel_launch(void* const* d_in, const int* in_sizes, int n_in,
                              void* d_out, int out_size, void* d_ws, size_t ws_size,
                              hipStream_t stream)
{
  (void)in_sizes; (void)n_in; (void)out_size;
  const float* x    = (const float*)d_in[0];
  const float* xc   = (const float*)d_in[1];
  const float* Wfx  = (const float*)d_in[2];
  const float* bfx  = (const float*)d_in[3];
  const float* Wx   = (const float*)d_in[4];
  const float* bx   = (const float*)d_in[5];
  const float* Wsl  = (const float*)d_in[6];
  const float* bsl  = (const float*)d_in[7];
  const float* temp = (const float*)d_in[8];
  const float* Wq   = (const float*)d_in[9];
  const float* Wk   = (const float*)d_in[10];
  const float* Wv   = (const float*)d_in[11];
  const float* Wo   = (const float*)d_in[12];
  const float* bo   = (const float*)d_in[13];
  float* out = (float*)d_out;

  float* ws  = (float*)d_ws;
  float* Sx  = ws;                 // 2048
  float* Sc  = Sx + 2048;          // 2048
  float* TUx = Sc + 2048;          // 131072
  float* TUc = TUx + 131072;       // 131072
  float* OT  = TUc + 131072;       // 131072
  _Float16* WoTth = (_Float16*)(OT + 131072);   // 524288 f16 [bh][co][g]
  _Float16* WoTtl = WoTth + 524288;             // 524288 f16
  _Float16* Wxth  = WoTtl + 524288;             // 131072 f16 [col][k]
  _Float16* Wxtl  = Wxth + 131072;              // 131072 f16
  _Float16* Xic   = Wxtl + 131072;              // xc planes: 67,108,864 f16 = 134 MB

  const size_t baseBytes = (size_t)((char*)Xic - (char*)d_ws);  // 4,210,688
  const size_t planeBytes = (size_t)Bc * Nc * 512 * sizeof(_Float16);
  const bool xcFits = ws_size >= baseBytes + planeBytes;

  _Float16* XiOut = (_Float16*)d_out;  // x planes overlay the output buffer

  hipMemsetAsync(Sx, 0, (size_t)(2 * 2048 + 2 * 131072) * sizeof(float), stream);

  xplanes_kernel<<<dim3(16384), 256, 0, stream>>>(x, XiOut);
  if (xcFits) xplanes_kernel<<<dim3(16384), 256, 0, stream>>>(xc, Xic);
  wxprep_kernel<<<dim3(4, 8), 256, 0, stream>>>(Wx, Wxth, Wxtl);
  project_token_kernel<<<dim3(16, 8, 8), 256, 0, stream>>>(
      x, xc, XiOut, xcFits ? Xic : (const _Float16*)nullptr,
      Wfx, bfx, Wx, bx, Wsl, bsl, temp, TUx, TUc, Sx, Sc);
  att_kernel<<<dim3(32), dim3(64), 0, stream>>>(TUx, TUc, Sx, Sc, Wq, Wk, Wv, OT);
  wofold_kernel<<<dim3(4, 32), 256, 0, stream>>>(OT, Wo, WoTth, WoTtl);
  outx_kernel<<<dim3(512, 4), 256, 0, stream>>>(XiOut, Wxth, Wxtl, bx, Wsl, bsl, temp,
                                                WoTth, WoTtl, bo, out);
}